// Round 2
// 414.794 us; speedup vs baseline: 1.1294x; 1.1294x over previous
//
#include <hip/hip_runtime.h>

// GraphSAGE link predictor, bf16-MFMA edition.
//   h = relu( mean_agg(x)@w1l.T + b1 + x@w1r.T )
//   z = mean_agg(h)@w2l.T + b2 + h@w2r.T
//   out[e] = dot(z[src[e]], z[dst[e]])
//
// R4: XCD-partitioned CSR build. R5: bf16 MFMA GEMMs. R6: bf16 z + fused
//     layer-1 GEMM (agg-then-project).
// R7: counters showed fill_csr (73us, 21% HBM, VALU 4.5%) = atomic-latency
//     bound, and the exact-CSR build needs TWO edge scans (count+fill) plus
//     scans. Degrees are Poisson(16), max ~40 << 64, so switch to PADDED CSR
//     (64 slots/node): one pass does count AND fill (rank = atomicAdd return).
//     Deletes count_deg + 3 scan kernels (~70us). Ranks are sequential so
//     writes stay dense (1 line/node). int4 NT loads of the dst stream give
//     4 independent atomic chains/thread and stop streaming reads from
//     evicting csr lines in L2. hlb/hrb/zb alias dead xb/ag1 regions.
// R7b: compile fix — __builtin_nontemporal_load needs a clang ext_vector
//      pointer, not HIP_vector_type<int,4>.
//
// edge_index arrives as int32 (harness converts int64 inputs).

#define IN_C      128
#define HID_C     128
#define OUT_C     64
#define NPART     8
#define SLICE_E   4096
#define CAP       64     // padded-CSR slots/node. Poisson(16): P(deg>63)~1e-17.

typedef unsigned short u16;
typedef __attribute__((ext_vector_type(8))) __bf16 bf16x8;
typedef __attribute__((ext_vector_type(4))) float f32x4;
typedef __attribute__((ext_vector_type(4))) int i32x4;

__device__ inline u16 f2bf(float f) {                 // RNE f32 -> bf16
    unsigned u = __float_as_uint(f);
    u += 0x7fff + ((u >> 16) & 1);
    return (u16)(u >> 16);
}
__device__ inline float bflo(unsigned v) { return __uint_as_float(v << 16); }
__device__ inline float bfhi(unsigned v) { return __uint_as_float(v & 0xffff0000u); }

// ---------------------------------------------------------------- padded-CSR build
// One pass: rank = atomicAdd(cnt[d]) gives the slot directly. blockIdx&7 ==
// XCD id under round-robin dispatch, so each dst-range's cnt+csr lines stay
// in ONE XCD's L2 (atomics local, writes merge).
__global__ __launch_bounds__(256) void fill_pad(const int* __restrict__ ei,
                                                int* __restrict__ cnt,
                                                int* __restrict__ csr, int E, int n) {
    const int range = blockIdx.x & (NPART - 1);
    const int slice = blockIdx.x >> 3;
    const int nr = (n + NPART - 1) / NPART;
    const int lo = range * nr;
    const int hi = min(n, lo + nr);
    const int base = slice * SLICE_E;
    const int e1 = min(E, base + SLICE_E);
    for (int e = base + threadIdx.x * 4; e < e1; e += 1024) {
        i32x4 d4 = __builtin_nontemporal_load((const i32x4*)(ei + (size_t)E + e));
#pragma unroll
        for (int j = 0; j < 4; ++j) {
            int d = d4[j];
            if (d >= lo && d < hi) {
                int s = __builtin_nontemporal_load(ei + e + j);
                int r = atomicAdd(&cnt[d], 1);
                if (r < CAP && (unsigned)s < (unsigned)n)
                    csr[(size_t)d * CAP + r] = s;
            }
        }
    }
}

__global__ __launch_bounds__(256) void deg_inv(const int* __restrict__ cnt,
                                               float* __restrict__ inv_deg, int n) {
    int i = blockIdx.x * 256 + threadIdx.x;
    if (i < n) inv_deg[i] = 1.0f / (float)max(cnt[i], 1);
}

// ---------------------------------------------------------------- converts
__global__ __launch_bounds__(256) void cvt_x(const float* __restrict__ in,
                                             u16* __restrict__ outb, int n4) {
    int i = blockIdx.x * 256 + threadIdx.x;
    if (i >= n4) return;
    float4 v = ((const float4*)in)[i];
    ushort4 o;
    o.x = f2bf(v.x); o.y = f2bf(v.y); o.z = f2bf(v.z); o.w = f2bf(v.w);
    ((ushort4*)outb)[i] = o;
}

// Wb1[c][0:128]=w1l[c], Wb1[c][128:256]=w1r[c]  -> [128][256] bf16
// Wb2 = cat(w2l,w2r)                             -> [128][128] bf16
__global__ __launch_bounds__(256) void cvt_w(const float* __restrict__ w1l,
                                             const float* __restrict__ w1r,
                                             const float* __restrict__ w2l,
                                             const float* __restrict__ w2r,
                                             u16* __restrict__ Wb1,
                                             u16* __restrict__ Wb2) {
    int i = blockIdx.x * 256 + threadIdx.x;
    if (i < 32768) {
        int c = i >> 8, k = i & 255;
        float v = (k < 128) ? w1l[c * 128 + k] : w1r[c * 128 + (k - 128)];
        Wb1[i] = f2bf(v);
    } else if (i < 49152) {
        int j = i - 32768;
        float v = (j < 8192) ? w2l[j] : w2r[j - 8192];
        Wb2[j] = f2bf(v);
    }
}

// ---------------------------------------------------------------- fused layer-1 GEMM
// h = relu([A0|A1] @ W.T + b), A0/A1 [n][128] bf16, W [128][256] bf16 -> h [n][128] bf16
// Frag facts (m89/m120): A[m=lane&15][k=quad*8+j], B[k=quad*8+j][n=lane&15],
// D: col=lane&15, row=quad*4+reg. Both frags = 8 contiguous k's of a row.
__global__ __launch_bounds__(256) void gemm_l1(const u16* __restrict__ A0,
                                               const u16* __restrict__ A1,
                                               const u16* __restrict__ Wb,
                                               const float* __restrict__ bias,
                                               u16* __restrict__ outp, int nrows) {
    constexpr int K    = 256;
    constexpr int COLS = 128;
    constexpr int KS   = K / 32;             // 8
    constexpr int NCT  = COLS / 16;          // 8
    constexpr int WROW = K + 8;
    __shared__ u16 wl[COLS * WROW];          // 67.6 KB

    const int t = threadIdx.x;
    for (int i = t; i < COLS * (K / 8); i += 256) {
        int r = i >> 5, p = i & 31;
        *(uint4*)&wl[r * WROW + p * 8] = *(const uint4*)&Wb[(size_t)r * K + p * 8];
    }
    __syncthreads();

    const int wv    = t >> 6;
    const int lane  = t & 63;
    const int cl    = lane & 15;
    const int quad  = lane >> 4;
    const int rbase = blockIdx.x * 128 + wv * 32;

    bf16x8 afrag[2][KS];
#pragma unroll
    for (int tile = 0; tile < 2; ++tile) {
        int r = min(rbase + tile * 16 + cl, nrows - 1);
        const u16* s0 = A0 + (size_t)r * 128 + quad * 8;
        const u16* s1 = A1 + (size_t)r * 128 + quad * 8;
#pragma unroll
        for (int ks = 0; ks < 4; ++ks) {
            afrag[tile][ks]     = *(const bf16x8*)(s0 + ks * 32);
            afrag[tile][4 + ks] = *(const bf16x8*)(s1 + ks * 32);
        }
    }

#pragma unroll
    for (int ct = 0; ct < NCT; ++ct) {
        f32x4 acc0 = {0.f, 0.f, 0.f, 0.f};
        f32x4 acc1 = {0.f, 0.f, 0.f, 0.f};
        const u16* wp = &wl[(ct * 16 + cl) * WROW + quad * 8];
#pragma unroll
        for (int ks = 0; ks < KS; ++ks) {
            bf16x8 bfrag = *(const bf16x8*)(wp + ks * 32);
            acc0 = __builtin_amdgcn_mfma_f32_16x16x32_bf16(afrag[0][ks], bfrag, acc0, 0, 0, 0);
            acc1 = __builtin_amdgcn_mfma_f32_16x16x32_bf16(afrag[1][ks], bfrag, acc1, 0, 0, 0);
        }
        int gc = ct * 16 + cl;
        float bv = bias[gc];
#pragma unroll
        for (int tile = 0; tile < 2; ++tile) {
            f32x4 a = tile ? acc1 : acc0;
#pragma unroll
            for (int r = 0; r < 4; ++r) {
                int row = rbase + tile * 16 + quad * 4 + r;
                if (row < nrows)
                    outp[(size_t)row * COLS + gc] = f2bf(fmaxf(a[r] + bv, 0.f));
            }
        }
    }
}

// ---------------------------------------------------------------- dual GEMM (layer 2)
// [outA | outB](bf16) = xb @ Wb.T ; outB += bias. Wb [2*COLS][K] bf16.
template <int K, int COLS>
__global__ __launch_bounds__(256) void gemm_mfma(const u16* __restrict__ xb,
                                                 const u16* __restrict__ Wb,
                                                 const float* __restrict__ bias,
                                                 u16* __restrict__ outA,
                                                 u16* __restrict__ outB,
                                                 int nrows) {
    constexpr int NCOL = 2 * COLS;
    constexpr int NCT  = NCOL / 16;
    constexpr int KS   = K / 32;
    constexpr int WROW = K + 8;
    __shared__ u16 wl[NCOL * WROW];

    const int t = threadIdx.x;
    for (int i = t; i < NCOL * (K / 8); i += 256) {
        int r = i / (K / 8), p = i % (K / 8);
        *(uint4*)&wl[r * WROW + p * 8] = *(const uint4*)&Wb[(size_t)r * K + p * 8];
    }
    __syncthreads();

    const int wv    = t >> 6;
    const int lane  = t & 63;
    const int cl    = lane & 15;
    const int quad  = lane >> 4;
    const int rbase = blockIdx.x * 128 + wv * 32;

    bf16x8 afrag[2][KS];
#pragma unroll
    for (int tile = 0; tile < 2; ++tile) {
        int r = rbase + tile * 16 + cl;
        const u16* src = xb + (size_t)min(r, nrows - 1) * K + quad * 8;
#pragma unroll
        for (int ks = 0; ks < KS; ++ks)
            afrag[tile][ks] = *(const bf16x8*)(src + ks * 32);
    }

#pragma unroll
    for (int ct = 0; ct < NCT; ++ct) {
        f32x4 acc0 = {0.f, 0.f, 0.f, 0.f};
        f32x4 acc1 = {0.f, 0.f, 0.f, 0.f};
        const u16* wp = &wl[(ct * 16 + cl) * WROW + quad * 8];
#pragma unroll
        for (int ks = 0; ks < KS; ++ks) {
            bf16x8 bfrag = *(const bf16x8*)(wp + ks * 32);
            acc0 = __builtin_amdgcn_mfma_f32_16x16x32_bf16(afrag[0][ks], bfrag, acc0, 0, 0, 0);
            acc1 = __builtin_amdgcn_mfma_f32_16x16x32_bf16(afrag[1][ks], bfrag, acc1, 0, 0, 0);
        }
        int gc = ct * 16 + cl;
        bool isA = gc < COLS;
        float bv = isA ? 0.f : bias[gc - COLS];
        u16* dst = isA ? (outA + gc) : (outB + (gc - COLS));
#pragma unroll
        for (int tile = 0; tile < 2; ++tile) {
            f32x4 a = tile ? acc1 : acc0;
#pragma unroll
            for (int r = 0; r < 4; ++r) {
                int row = rbase + tile * 16 + quad * 4 + r;
                if (row < nrows) dst[(size_t)row * COLS] = f2bf(a[r] + bv);
            }
        }
    }
}

// ---------------------------------------------------------------- aggregate
// out[n] = (sum_{s in csr_pad[n]} gl[s]) * inv_deg[n]  [+ other[n]] ; bf16 in/out.
// Padded CSR: node's edges at csr[node*CAP .. node*CAP+deg).
template <int C, bool HAS_OTHER>
__global__ __launch_bounds__(256) void agg_bf(const u16* __restrict__ gl,
                                              const u16* __restrict__ other,
                                              const int* __restrict__ cnt,
                                              const int* __restrict__ csr,
                                              const float* __restrict__ inv_deg,
                                              u16* __restrict__ outp, int n) {
    constexpr int G = C / 8;                 // lanes per node
    int t = threadIdx.x;
    int node = blockIdx.x * (256 / G) + t / G;
    int l = t % G;
    if (node >= n) return;

    int deg = min(cnt[node], CAP);
    const int* sp = csr + (size_t)node * CAP;
    float a[8] = {0.f, 0.f, 0.f, 0.f, 0.f, 0.f, 0.f, 0.f};
    const size_t coff = (size_t)l * 8;
    for (int p = 0; p < deg; ++p) {
        int s = sp[p];
        uint4 v = *(const uint4*)(gl + (size_t)s * C + coff);
        a[0] += bflo(v.x); a[1] += bfhi(v.x);
        a[2] += bflo(v.y); a[3] += bfhi(v.y);
        a[4] += bflo(v.z); a[5] += bfhi(v.z);
        a[6] += bflo(v.w); a[7] += bfhi(v.w);
    }
    float id = inv_deg[node];
    float r[8];
    if (HAS_OTHER) {
        uint4 o = *(const uint4*)(other + (size_t)node * C + coff);
        r[0] = fmaf(a[0], id, bflo(o.x)); r[1] = fmaf(a[1], id, bfhi(o.x));
        r[2] = fmaf(a[2], id, bflo(o.y)); r[3] = fmaf(a[3], id, bfhi(o.y));
        r[4] = fmaf(a[4], id, bflo(o.z)); r[5] = fmaf(a[5], id, bfhi(o.z));
        r[6] = fmaf(a[6], id, bflo(o.w)); r[7] = fmaf(a[7], id, bfhi(o.w));
    } else {
#pragma unroll
        for (int j = 0; j < 8; ++j) r[j] = a[j] * id;
    }
    uint4 w;
    w.x = (unsigned)f2bf(r[0]) | ((unsigned)f2bf(r[1]) << 16);
    w.y = (unsigned)f2bf(r[2]) | ((unsigned)f2bf(r[3]) << 16);
    w.z = (unsigned)f2bf(r[4]) | ((unsigned)f2bf(r[5]) << 16);
    w.w = (unsigned)f2bf(r[6]) | ((unsigned)f2bf(r[7]) << 16);
    *(uint4*)(outp + (size_t)node * C + coff) = w;
}

// ---------------------------------------------------------------- decode (bf16 z)
__global__ __launch_bounds__(256) void decode(const u16* __restrict__ z,
                                              const int* __restrict__ ei,
                                              float* __restrict__ out, int E, int n) {
    int t = blockIdx.x * 256 + threadIdx.x;
    int e = t >> 3, l = t & 7;
    if (e >= E) return;
    int s = __builtin_nontemporal_load(ei + e);
    int d = __builtin_nontemporal_load(ei + (size_t)E + e);
    float p = 0.f;
    if ((unsigned)s < (unsigned)n && (unsigned)d < (unsigned)n) {
        uint4 a = *(const uint4*)(z + (size_t)s * OUT_C + l * 8);
        uint4 b = *(const uint4*)(z + (size_t)d * OUT_C + l * 8);
        p  = bflo(a.x) * bflo(b.x) + bfhi(a.x) * bfhi(b.x);
        p += bflo(a.y) * bflo(b.y) + bfhi(a.y) * bfhi(b.y);
        p += bflo(a.z) * bflo(b.z) + bfhi(a.z) * bfhi(b.z);
        p += bflo(a.w) * bflo(b.w) + bfhi(a.w) * bfhi(b.w);
    }
    p += __shfl_xor(p, 4);
    p += __shfl_xor(p, 2);
    p += __shfl_xor(p, 1);
    if (l == 0) out[e] = p;
}

// ---------------------------------------------------------------- launch
extern "C" void kernel_launch(void* const* d_in, const int* in_sizes, int n_in,
                              void* d_out, int out_size, void* d_ws, size_t ws_size,
                              hipStream_t stream) {
    const float* x   = (const float*)d_in[0];
    const int*   ei  = (const int*)d_in[1];
    const float* w1l = (const float*)d_in[2];
    const float* w1r = (const float*)d_in[3];
    const float* b1  = (const float*)d_in[4];
    const float* w2l = (const float*)d_in[5];
    const float* w2r = (const float*)d_in[6];
    const float* b2  = (const float*)d_in[7];
    float*       out = (float*)d_out;

    const int N = in_sizes[0] / IN_C;
    const int E = in_sizes[1] / 2;

    auto alignup = [](size_t v) { return (v + 255) & ~(size_t)255; };
    char* p = (char*)d_ws;
    int*   cnt       = (int*)p;   p += alignup((size_t)N * 4);
    float* inv_deg   = (float*)p; p += alignup((size_t)N * 4);
    int*   csr       = (int*)p;   p += alignup((size_t)N * CAP * 4);   // 25.6 MB
    u16*   Wb1       = (u16*)p;   p += alignup((size_t)HID_C * 2 * IN_C * 2);
    u16*   Wb2       = (u16*)p;   p += alignup((size_t)2 * OUT_C * HID_C * 2);
    u16*   xb        = (u16*)p;   p += alignup((size_t)N * IN_C * 2);  // dead after gemm_l1
    u16*   ag1       = (u16*)p;   p += alignup((size_t)N * HID_C * 2); // dead after gemm_l1
    u16*   hb        = (u16*)p;   p += alignup((size_t)N * HID_C * 2);
    // alias late-stage buffers onto dead xb/ag1 regions
    u16*   hlb       = xb;                              // N*OUT_C*2 = 12.8 MB
    u16*   hrb       = xb + (size_t)N * OUT_C;          // second half of xb region
    u16*   zb        = ag1;                             // 12.8 MB in ag1 region

    const int nslice = (E + SLICE_E - 1) / SLICE_E;

    // converts (independent of CSR)
    cvt_x<<<(N * IN_C / 4 + 255) / 256, 256, 0, stream>>>(x, xb, N * IN_C / 4);
    cvt_w<<<192, 256, 0, stream>>>(w1l, w1r, w2l, w2r, Wb1, Wb2);

    // padded-CSR build: ONE edge pass (count==fill), XCD-partitioned by dst range
    hipMemsetAsync(cnt, 0, (size_t)N * 4, stream);
    fill_pad<<<nslice * NPART, 256, 0, stream>>>(ei, cnt, csr, E, N);
    deg_inv<<<(N + 255) / 256, 256, 0, stream>>>(cnt, inv_deg, N);

    const int rb = (N + 127) / 128;

    // ag1 = mean_agg(xb)
    agg_bf<HID_C, false><<<(N + 15) / 16, 256, 0, stream>>>(xb, nullptr, cnt, csr,
                                                            inv_deg, ag1, N);
    // h = relu([ag1|xb] @ [w1l|w1r].T + b1)
    gemm_l1<<<rb, 256, 0, stream>>>(ag1, xb, Wb1, b1, hb, N);

    // hl = h@w2l.T ; hr = h@w2r.T + b2
    gemm_mfma<HID_C, OUT_C><<<rb, 256, 0, stream>>>(hb, Wb2, b2, hlb, hrb, N);
    // z = agg(hl)/deg + hr  (bf16)
    agg_bf<OUT_C, true><<<(N + 31) / 32, 256, 0, stream>>>(hlb, hrb, cnt, csr,
                                                           inv_deg, zb, N);

    // decode (bf16 z)
    decode<<<((size_t)E * 8 + 255) / 256, 256, 0, stream>>>(zb, ei, out, E, N);
}

// Round 3
// 412.221 us; speedup vs baseline: 1.1364x; 1.0062x over previous
//
#include <hip/hip_runtime.h>

// GraphSAGE link predictor, bf16-MFMA edition.
//   h = relu( mean_agg(x)@w1l.T + b1 + x@w1r.T )
//   z = mean_agg(h)@w2l.T + b2 + h@w2r.T
//   out[e] = dot(z[src[e]], z[dst[e]])
//
// R4: XCD-partitioned CSR build. R5: bf16 MFMA GEMMs. R6: bf16 z + fused
//     layer-1 GEMM (agg-then-project).
// R7: padded CSR (CAP=64, Poisson(16) max deg ~40): one edge pass does
//     count AND fill (rank = atomicAdd return). Deleted count_deg + scans.
// R8: R7 counters: fill_pad 86us @ 20% HBM, VALU 4% = latency-bound, NOT
//     BW-bound. Chain was: NT dst4 load -> scalar src gather (8/64 lanes)
//     -> atomic -> dependent store, x4 sequential rounds. Restructure for
//     MLP: issue ALL 8 vector loads (4x dst4 + 4x src4) upfront, then 16
//     independent {cmp, atomicAdd, store} bodies. src4 unconditional is
//     ~free traffic-wise (88% of src lines have a match per XCD pass).
//
// edge_index arrives as int32 (harness converts int64 inputs).

#define IN_C      128
#define HID_C     128
#define OUT_C     64
#define NPART     8
#define SLICE_E   4096
#define CAP       64     // padded-CSR slots/node. Poisson(16): P(deg>63)~1e-17.

typedef unsigned short u16;
typedef __attribute__((ext_vector_type(8))) __bf16 bf16x8;
typedef __attribute__((ext_vector_type(4))) float f32x4;
typedef __attribute__((ext_vector_type(4))) int i32x4;

__device__ inline u16 f2bf(float f) {                 // RNE f32 -> bf16
    unsigned u = __float_as_uint(f);
    u += 0x7fff + ((u >> 16) & 1);
    return (u16)(u >> 16);
}
__device__ inline float bflo(unsigned v) { return __uint_as_float(v << 16); }
__device__ inline float bfhi(unsigned v) { return __uint_as_float(v & 0xffff0000u); }

// ---------------------------------------------------------------- padded-CSR build
// One pass: rank = atomicAdd(cnt[d]) gives the slot directly. blockIdx&7 ==
// XCD id under round-robin dispatch, so each dst-range's cnt+csr lines stay
// in ONE XCD's L2 (atomics local, writes merge). All loads hoisted for MLP.
__global__ __launch_bounds__(256) void fill_pad(const int* __restrict__ ei,
                                                int* __restrict__ cnt,
                                                int* __restrict__ csr, int E, int n) {
    const int range = blockIdx.x & (NPART - 1);
    const int slice = blockIdx.x >> 3;
    const int nr = (n + NPART - 1) / NPART;
    const int lo = range * nr;
    const int hi = min(n, lo + nr);
    const int base = slice * SLICE_E + threadIdx.x * 4;

    i32x4 d4[4], s4[4];
#pragma unroll
    for (int i = 0; i < 4; ++i) {
        int e = base + i * 1024;
        if (e < E) {   // e%4==0 and E%4==0 => full int4 in bounds
            d4[i] = __builtin_nontemporal_load((const i32x4*)(ei + (size_t)E + e));
            s4[i] = __builtin_nontemporal_load((const i32x4*)(ei + e));
        } else {
            d4[i] = (i32x4)(-1);
            s4[i] = (i32x4)(0);
        }
    }

#pragma unroll
    for (int i = 0; i < 4; ++i) {
#pragma unroll
        for (int j = 0; j < 4; ++j) {
            int d = d4[i][j];
            if (d >= lo && d < hi) {
                int s = s4[i][j];
                int r = atomicAdd(&cnt[d], 1);
                if (r < CAP && (unsigned)s < (unsigned)n)
                    csr[(size_t)d * CAP + r] = s;
            }
        }
    }
}

__global__ __launch_bounds__(256) void deg_inv(const int* __restrict__ cnt,
                                               float* __restrict__ inv_deg, int n) {
    int i = blockIdx.x * 256 + threadIdx.x;
    if (i < n) inv_deg[i] = 1.0f / (float)max(cnt[i], 1);
}

// ---------------------------------------------------------------- converts
__global__ __launch_bounds__(256) void cvt_x(const float* __restrict__ in,
                                             u16* __restrict__ outb, int n4) {
    int i = blockIdx.x * 256 + threadIdx.x;
    if (i >= n4) return;
    float4 v = ((const float4*)in)[i];
    ushort4 o;
    o.x = f2bf(v.x); o.y = f2bf(v.y); o.z = f2bf(v.z); o.w = f2bf(v.w);
    ((ushort4*)outb)[i] = o;
}

// Wb1[c][0:128]=w1l[c], Wb1[c][128:256]=w1r[c]  -> [128][256] bf16
// Wb2 = cat(w2l,w2r)                             -> [128][128] bf16
__global__ __launch_bounds__(256) void cvt_w(const float* __restrict__ w1l,
                                             const float* __restrict__ w1r,
                                             const float* __restrict__ w2l,
                                             const float* __restrict__ w2r,
                                             u16* __restrict__ Wb1,
                                             u16* __restrict__ Wb2) {
    int i = blockIdx.x * 256 + threadIdx.x;
    if (i < 32768) {
        int c = i >> 8, k = i & 255;
        float v = (k < 128) ? w1l[c * 128 + k] : w1r[c * 128 + (k - 128)];
        Wb1[i] = f2bf(v);
    } else if (i < 49152) {
        int j = i - 32768;
        float v = (j < 8192) ? w2l[j] : w2r[j - 8192];
        Wb2[j] = f2bf(v);
    }
}

// ---------------------------------------------------------------- fused layer-1 GEMM
// h = relu([A0|A1] @ W.T + b), A0/A1 [n][128] bf16, W [128][256] bf16 -> h [n][128] bf16
// Frag facts (m89/m120): A[m=lane&15][k=quad*8+j], B[k=quad*8+j][n=lane&15],
// D: col=lane&15, row=quad*4+reg. Both frags = 8 contiguous k's of a row.
__global__ __launch_bounds__(256) void gemm_l1(const u16* __restrict__ A0,
                                               const u16* __restrict__ A1,
                                               const u16* __restrict__ Wb,
                                               const float* __restrict__ bias,
                                               u16* __restrict__ outp, int nrows) {
    constexpr int K    = 256;
    constexpr int COLS = 128;
    constexpr int KS   = K / 32;             // 8
    constexpr int NCT  = COLS / 16;          // 8
    constexpr int WROW = K + 8;
    __shared__ u16 wl[COLS * WROW];          // 67.6 KB

    const int t = threadIdx.x;
    for (int i = t; i < COLS * (K / 8); i += 256) {
        int r = i >> 5, p = i & 31;
        *(uint4*)&wl[r * WROW + p * 8] = *(const uint4*)&Wb[(size_t)r * K + p * 8];
    }
    __syncthreads();

    const int wv    = t >> 6;
    const int lane  = t & 63;
    const int cl    = lane & 15;
    const int quad  = lane >> 4;
    const int rbase = blockIdx.x * 128 + wv * 32;

    bf16x8 afrag[2][KS];
#pragma unroll
    for (int tile = 0; tile < 2; ++tile) {
        int r = min(rbase + tile * 16 + cl, nrows - 1);
        const u16* s0 = A0 + (size_t)r * 128 + quad * 8;
        const u16* s1 = A1 + (size_t)r * 128 + quad * 8;
#pragma unroll
        for (int ks = 0; ks < 4; ++ks) {
            afrag[tile][ks]     = *(const bf16x8*)(s0 + ks * 32);
            afrag[tile][4 + ks] = *(const bf16x8*)(s1 + ks * 32);
        }
    }

#pragma unroll
    for (int ct = 0; ct < NCT; ++ct) {
        f32x4 acc0 = {0.f, 0.f, 0.f, 0.f};
        f32x4 acc1 = {0.f, 0.f, 0.f, 0.f};
        const u16* wp = &wl[(ct * 16 + cl) * WROW + quad * 8];
#pragma unroll
        for (int ks = 0; ks < KS; ++ks) {
            bf16x8 bfrag = *(const bf16x8*)(wp + ks * 32);
            acc0 = __builtin_amdgcn_mfma_f32_16x16x32_bf16(afrag[0][ks], bfrag, acc0, 0, 0, 0);
            acc1 = __builtin_amdgcn_mfma_f32_16x16x32_bf16(afrag[1][ks], bfrag, acc1, 0, 0, 0);
        }
        int gc = ct * 16 + cl;
        float bv = bias[gc];
#pragma unroll
        for (int tile = 0; tile < 2; ++tile) {
            f32x4 a = tile ? acc1 : acc0;
#pragma unroll
            for (int r = 0; r < 4; ++r) {
                int row = rbase + tile * 16 + quad * 4 + r;
                if (row < nrows)
                    outp[(size_t)row * COLS + gc] = f2bf(fmaxf(a[r] + bv, 0.f));
            }
        }
    }
}

// ---------------------------------------------------------------- dual GEMM (layer 2)
// [outA | outB](bf16) = xb @ Wb.T ; outB += bias. Wb [2*COLS][K] bf16.
template <int K, int COLS>
__global__ __launch_bounds__(256) void gemm_mfma(const u16* __restrict__ xb,
                                                 const u16* __restrict__ Wb,
                                                 const float* __restrict__ bias,
                                                 u16* __restrict__ outA,
                                                 u16* __restrict__ outB,
                                                 int nrows) {
    constexpr int NCOL = 2 * COLS;
    constexpr int NCT  = NCOL / 16;
    constexpr int KS   = K / 32;
    constexpr int WROW = K + 8;
    __shared__ u16 wl[NCOL * WROW];

    const int t = threadIdx.x;
    for (int i = t; i < NCOL * (K / 8); i += 256) {
        int r = i / (K / 8), p = i % (K / 8);
        *(uint4*)&wl[r * WROW + p * 8] = *(const uint4*)&Wb[(size_t)r * K + p * 8];
    }
    __syncthreads();

    const int wv    = t >> 6;
    const int lane  = t & 63;
    const int cl    = lane & 15;
    const int quad  = lane >> 4;
    const int rbase = blockIdx.x * 128 + wv * 32;

    bf16x8 afrag[2][KS];
#pragma unroll
    for (int tile = 0; tile < 2; ++tile) {
        int r = rbase + tile * 16 + cl;
        const u16* src = xb + (size_t)min(r, nrows - 1) * K + quad * 8;
#pragma unroll
        for (int ks = 0; ks < KS; ++ks)
            afrag[tile][ks] = *(const bf16x8*)(src + ks * 32);
    }

#pragma unroll
    for (int ct = 0; ct < NCT; ++ct) {
        f32x4 acc0 = {0.f, 0.f, 0.f, 0.f};
        f32x4 acc1 = {0.f, 0.f, 0.f, 0.f};
        const u16* wp = &wl[(ct * 16 + cl) * WROW + quad * 8];
#pragma unroll
        for (int ks = 0; ks < KS; ++ks) {
            bf16x8 bfrag = *(const bf16x8*)(wp + ks * 32);
            acc0 = __builtin_amdgcn_mfma_f32_16x16x32_bf16(afrag[0][ks], bfrag, acc0, 0, 0, 0);
            acc1 = __builtin_amdgcn_mfma_f32_16x16x32_bf16(afrag[1][ks], bfrag, acc1, 0, 0, 0);
        }
        int gc = ct * 16 + cl;
        bool isA = gc < COLS;
        float bv = isA ? 0.f : bias[gc - COLS];
        u16* dst = isA ? (outA + gc) : (outB + (gc - COLS));
#pragma unroll
        for (int tile = 0; tile < 2; ++tile) {
            f32x4 a = tile ? acc1 : acc0;
#pragma unroll
            for (int r = 0; r < 4; ++r) {
                int row = rbase + tile * 16 + quad * 4 + r;
                if (row < nrows) dst[(size_t)row * COLS] = f2bf(a[r] + bv);
            }
        }
    }
}

// ---------------------------------------------------------------- aggregate
// out[n] = (sum_{s in csr_pad[n]} gl[s]) * inv_deg[n]  [+ other[n]] ; bf16 in/out.
// Padded CSR: node's edges at csr[node*CAP .. node*CAP+deg).
template <int C, bool HAS_OTHER>
__global__ __launch_bounds__(256) void agg_bf(const u16* __restrict__ gl,
                                              const u16* __restrict__ other,
                                              const int* __restrict__ cnt,
                                              const int* __restrict__ csr,
                                              const float* __restrict__ inv_deg,
                                              u16* __restrict__ outp, int n) {
    constexpr int G = C / 8;                 // lanes per node
    int t = threadIdx.x;
    int node = blockIdx.x * (256 / G) + t / G;
    int l = t % G;
    if (node >= n) return;

    int deg = min(cnt[node], CAP);
    const int* sp = csr + (size_t)node * CAP;
    float a[8] = {0.f, 0.f, 0.f, 0.f, 0.f, 0.f, 0.f, 0.f};
    const size_t coff = (size_t)l * 8;
    for (int p = 0; p < deg; ++p) {
        int s = sp[p];
        uint4 v = *(const uint4*)(gl + (size_t)s * C + coff);
        a[0] += bflo(v.x); a[1] += bfhi(v.x);
        a[2] += bflo(v.y); a[3] += bfhi(v.y);
        a[4] += bflo(v.z); a[5] += bfhi(v.z);
        a[6] += bflo(v.w); a[7] += bfhi(v.w);
    }
    float id = inv_deg[node];
    float r[8];
    if (HAS_OTHER) {
        uint4 o = *(const uint4*)(other + (size_t)node * C + coff);
        r[0] = fmaf(a[0], id, bflo(o.x)); r[1] = fmaf(a[1], id, bfhi(o.x));
        r[2] = fmaf(a[2], id, bflo(o.y)); r[3] = fmaf(a[3], id, bfhi(o.y));
        r[4] = fmaf(a[4], id, bflo(o.z)); r[5] = fmaf(a[5], id, bfhi(o.z));
        r[6] = fmaf(a[6], id, bflo(o.w)); r[7] = fmaf(a[7], id, bfhi(o.w));
    } else {
#pragma unroll
        for (int j = 0; j < 8; ++j) r[j] = a[j] * id;
    }
    uint4 w;
    w.x = (unsigned)f2bf(r[0]) | ((unsigned)f2bf(r[1]) << 16);
    w.y = (unsigned)f2bf(r[2]) | ((unsigned)f2bf(r[3]) << 16);
    w.z = (unsigned)f2bf(r[4]) | ((unsigned)f2bf(r[5]) << 16);
    w.w = (unsigned)f2bf(r[6]) | ((unsigned)f2bf(r[7]) << 16);
    *(uint4*)(outp + (size_t)node * C + coff) = w;
}

// ---------------------------------------------------------------- decode (bf16 z)
__global__ __launch_bounds__(256) void decode(const u16* __restrict__ z,
                                              const int* __restrict__ ei,
                                              float* __restrict__ out, int E, int n) {
    int t = blockIdx.x * 256 + threadIdx.x;
    int e = t >> 3, l = t & 7;
    if (e >= E) return;
    int s = __builtin_nontemporal_load(ei + e);
    int d = __builtin_nontemporal_load(ei + (size_t)E + e);
    float p = 0.f;
    if ((unsigned)s < (unsigned)n && (unsigned)d < (unsigned)n) {
        uint4 a = *(const uint4*)(z + (size_t)s * OUT_C + l * 8);
        uint4 b = *(const uint4*)(z + (size_t)d * OUT_C + l * 8);
        p  = bflo(a.x) * bflo(b.x) + bfhi(a.x) * bfhi(b.x);
        p += bflo(a.y) * bflo(b.y) + bfhi(a.y) * bfhi(b.y);
        p += bflo(a.z) * bflo(b.z) + bfhi(a.z) * bfhi(b.z);
        p += bflo(a.w) * bflo(b.w) + bfhi(a.w) * bfhi(b.w);
    }
    p += __shfl_xor(p, 4);
    p += __shfl_xor(p, 2);
    p += __shfl_xor(p, 1);
    if (l == 0) out[e] = p;
}

// ---------------------------------------------------------------- launch
extern "C" void kernel_launch(void* const* d_in, const int* in_sizes, int n_in,
                              void* d_out, int out_size, void* d_ws, size_t ws_size,
                              hipStream_t stream) {
    const float* x   = (const float*)d_in[0];
    const int*   ei  = (const int*)d_in[1];
    const float* w1l = (const float*)d_in[2];
    const float* w1r = (const float*)d_in[3];
    const float* b1  = (const float*)d_in[4];
    const float* w2l = (const float*)d_in[5];
    const float* w2r = (const float*)d_in[6];
    const float* b2  = (const float*)d_in[7];
    float*       out = (float*)d_out;

    const int N = in_sizes[0] / IN_C;
    const int E = in_sizes[1] / 2;

    auto alignup = [](size_t v) { return (v + 255) & ~(size_t)255; };
    char* p = (char*)d_ws;
    int*   cnt       = (int*)p;   p += alignup((size_t)N * 4);
    float* inv_deg   = (float*)p; p += alignup((size_t)N * 4);
    int*   csr       = (int*)p;   p += alignup((size_t)N * CAP * 4);   // 25.6 MB
    u16*   Wb1       = (u16*)p;   p += alignup((size_t)HID_C * 2 * IN_C * 2);
    u16*   Wb2       = (u16*)p;   p += alignup((size_t)2 * OUT_C * HID_C * 2);
    u16*   xb        = (u16*)p;   p += alignup((size_t)N * IN_C * 2);  // dead after gemm_l1
    u16*   ag1       = (u16*)p;   p += alignup((size_t)N * HID_C * 2); // dead after gemm_l1
    u16*   hb        = (u16*)p;   p += alignup((size_t)N * HID_C * 2);
    // alias late-stage buffers onto dead xb/ag1 regions
    u16*   hlb       = xb;                              // N*OUT_C*2 = 12.8 MB
    u16*   hrb       = xb + (size_t)N * OUT_C;          // second half of xb region
    u16*   zb        = ag1;                             // 12.8 MB in ag1 region

    const int nslice = (E + SLICE_E - 1) / SLICE_E;

    // converts (independent of CSR)
    cvt_x<<<(N * IN_C / 4 + 255) / 256, 256, 0, stream>>>(x, xb, N * IN_C / 4);
    cvt_w<<<192, 256, 0, stream>>>(w1l, w1r, w2l, w2r, Wb1, Wb2);

    // padded-CSR build: ONE edge pass (count==fill), XCD-partitioned by dst range
    hipMemsetAsync(cnt, 0, (size_t)N * 4, stream);
    fill_pad<<<nslice * NPART, 256, 0, stream>>>(ei, cnt, csr, E, N);
    deg_inv<<<(N + 255) / 256, 256, 0, stream>>>(cnt, inv_deg, N);

    const int rb = (N + 127) / 128;

    // ag1 = mean_agg(xb)
    agg_bf<HID_C, false><<<(N + 15) / 16, 256, 0, stream>>>(xb, nullptr, cnt, csr,
                                                            inv_deg, ag1, N);
    // h = relu([ag1|xb] @ [w1l|w1r].T + b1)
    gemm_l1<<<rb, 256, 0, stream>>>(ag1, xb, Wb1, b1, hb, N);

    // hl = h@w2l.T ; hr = h@w2r.T + b2
    gemm_mfma<HID_C, OUT_C><<<rb, 256, 0, stream>>>(hb, Wb2, b2, hlb, hrb, N);
    // z = agg(hl)/deg + hr  (bf16)
    agg_bf<OUT_C, true><<<(N + 31) / 32, 256, 0, stream>>>(hlb, hrb, cnt, csr,
                                                           inv_deg, zb, N);

    // decode (bf16 z)
    decode<<<((size_t)E * 8 + 255) / 256, 256, 0, stream>>>(zb, ei, out, E, N);
}

// Round 4
// 409.742 us; speedup vs baseline: 1.1433x; 1.0060x over previous
//
#include <hip/hip_runtime.h>

// GraphSAGE link predictor, bf16-MFMA edition.
//   h = relu( mean_agg(x)@w1l.T + b1 + x@w1r.T )
//   z = mean_agg(h)@w2l.T + b2 + h@w2r.T
//   out[e] = dot(z[src[e]], z[dst[e]])
//
// R4: XCD-partitioned CSR build. R5: bf16 MFMA GEMMs. R6: bf16 z + fused
//     layer-1 GEMM (agg-then-project).
// R7: padded CSR (CAP=64): one edge pass does count AND fill (rank =
//     atomicAdd return). Deleted count_deg + scans.
// R8: hoisted all 8 vector loads upfront -> neutral (86->84us). FETCH fell
//     67->50MB so loads were NOT the critical path.
// R9: the chain is the ATOMIC: each unrolled body was atomicAdd (wait for
//     return, ~600cyc) -> dependent store, serialized x16 per wave. Split
//     into two loops: (1) issue all 16 exec-masked atomicAdds back-to-back
//     into rr[16]; (2) one waitcnt, then 16 independent stores. One atomic
//     round-trip per wave instead of ~16.
//
// edge_index arrives as int32 (harness converts int64 inputs).

#define IN_C      128
#define HID_C     128
#define OUT_C     64
#define NPART     8
#define SLICE_E   4096
#define CAP       64     // padded-CSR slots/node. Poisson(16): P(deg>63)~1e-17.

typedef unsigned short u16;
typedef __attribute__((ext_vector_type(8))) __bf16 bf16x8;
typedef __attribute__((ext_vector_type(4))) float f32x4;
typedef __attribute__((ext_vector_type(4))) int i32x4;

__device__ inline u16 f2bf(float f) {                 // RNE f32 -> bf16
    unsigned u = __float_as_uint(f);
    u += 0x7fff + ((u >> 16) & 1);
    return (u16)(u >> 16);
}
__device__ inline float bflo(unsigned v) { return __uint_as_float(v << 16); }
__device__ inline float bfhi(unsigned v) { return __uint_as_float(v & 0xffff0000u); }

// ---------------------------------------------------------------- padded-CSR build
// One pass: rank = atomicAdd(cnt[d]) gives the slot directly. blockIdx&7 ==
// XCD id under round-robin dispatch, so each dst-range's cnt+csr lines stay
// in ONE XCD's L2. Loads hoisted (R8); atomics hoisted off the store chain (R9).
__global__ __launch_bounds__(256) void fill_pad(const int* __restrict__ ei,
                                                int* __restrict__ cnt,
                                                int* __restrict__ csr, int E, int n) {
    const int range = blockIdx.x & (NPART - 1);
    const int slice = blockIdx.x >> 3;
    const int nr = (n + NPART - 1) / NPART;
    const int lo = range * nr;
    const int hi = min(n, lo + nr);
    const int base = slice * SLICE_E + threadIdx.x * 4;

    int dd[16], ss[16];
#pragma unroll
    for (int i = 0; i < 4; ++i) {
        int e = base + i * 1024;
        i32x4 d4, s4;
        if (e < E) {   // e%4==0 and E%4==0 => full int4 in bounds
            d4 = __builtin_nontemporal_load((const i32x4*)(ei + (size_t)E + e));
            s4 = __builtin_nontemporal_load((const i32x4*)(ei + e));
        } else {
            d4 = (i32x4)(-1);
            s4 = (i32x4)(0);
        }
#pragma unroll
        for (int j = 0; j < 4; ++j) { dd[i * 4 + j] = d4[j]; ss[i * 4 + j] = s4[j]; }
    }

    // phase 1: issue ALL rank-acquiring atomics; returns land in rr[].
    int rr[16];
#pragma unroll
    for (int k = 0; k < 16; ++k) {
        int d = dd[k];
        if (d >= lo && d < hi) rr[k] = atomicAdd(&cnt[d], 1);
    }
    // phase 2: one wait, then independent scatter stores.
#pragma unroll
    for (int k = 0; k < 16; ++k) {
        int d = dd[k];
        if (d >= lo && d < hi) {
            int s = ss[k];
            int r = rr[k];
            if (r < CAP && (unsigned)s < (unsigned)n)
                csr[(size_t)d * CAP + r] = s;
        }
    }
}

__global__ __launch_bounds__(256) void deg_inv(const int* __restrict__ cnt,
                                               float* __restrict__ inv_deg, int n) {
    int i = blockIdx.x * 256 + threadIdx.x;
    if (i < n) inv_deg[i] = 1.0f / (float)max(cnt[i], 1);
}

// ---------------------------------------------------------------- converts
__global__ __launch_bounds__(256) void cvt_x(const float* __restrict__ in,
                                             u16* __restrict__ outb, int n4) {
    int i = blockIdx.x * 256 + threadIdx.x;
    if (i >= n4) return;
    float4 v = ((const float4*)in)[i];
    ushort4 o;
    o.x = f2bf(v.x); o.y = f2bf(v.y); o.z = f2bf(v.z); o.w = f2bf(v.w);
    ((ushort4*)outb)[i] = o;
}

// Wb1[c][0:128]=w1l[c], Wb1[c][128:256]=w1r[c]  -> [128][256] bf16
// Wb2 = cat(w2l,w2r)                             -> [128][128] bf16
__global__ __launch_bounds__(256) void cvt_w(const float* __restrict__ w1l,
                                             const float* __restrict__ w1r,
                                             const float* __restrict__ w2l,
                                             const float* __restrict__ w2r,
                                             u16* __restrict__ Wb1,
                                             u16* __restrict__ Wb2) {
    int i = blockIdx.x * 256 + threadIdx.x;
    if (i < 32768) {
        int c = i >> 8, k = i & 255;
        float v = (k < 128) ? w1l[c * 128 + k] : w1r[c * 128 + (k - 128)];
        Wb1[i] = f2bf(v);
    } else if (i < 49152) {
        int j = i - 32768;
        float v = (j < 8192) ? w2l[j] : w2r[j - 8192];
        Wb2[j] = f2bf(v);
    }
}

// ---------------------------------------------------------------- fused layer-1 GEMM
// h = relu([A0|A1] @ W.T + b), A0/A1 [n][128] bf16, W [128][256] bf16 -> h [n][128] bf16
// Frag facts (m89/m120): A[m=lane&15][k=quad*8+j], B[k=quad*8+j][n=lane&15],
// D: col=lane&15, row=quad*4+reg. Both frags = 8 contiguous k's of a row.
__global__ __launch_bounds__(256) void gemm_l1(const u16* __restrict__ A0,
                                               const u16* __restrict__ A1,
                                               const u16* __restrict__ Wb,
                                               const float* __restrict__ bias,
                                               u16* __restrict__ outp, int nrows) {
    constexpr int K    = 256;
    constexpr int COLS = 128;
    constexpr int KS   = K / 32;             // 8
    constexpr int NCT  = COLS / 16;          // 8
    constexpr int WROW = K + 8;
    __shared__ u16 wl[COLS * WROW];          // 67.6 KB

    const int t = threadIdx.x;
    for (int i = t; i < COLS * (K / 8); i += 256) {
        int r = i >> 5, p = i & 31;
        *(uint4*)&wl[r * WROW + p * 8] = *(const uint4*)&Wb[(size_t)r * K + p * 8];
    }
    __syncthreads();

    const int wv    = t >> 6;
    const int lane  = t & 63;
    const int cl    = lane & 15;
    const int quad  = lane >> 4;
    const int rbase = blockIdx.x * 128 + wv * 32;

    bf16x8 afrag[2][KS];
#pragma unroll
    for (int tile = 0; tile < 2; ++tile) {
        int r = min(rbase + tile * 16 + cl, nrows - 1);
        const u16* s0 = A0 + (size_t)r * 128 + quad * 8;
        const u16* s1 = A1 + (size_t)r * 128 + quad * 8;
#pragma unroll
        for (int ks = 0; ks < 4; ++ks) {
            afrag[tile][ks]     = *(const bf16x8*)(s0 + ks * 32);
            afrag[tile][4 + ks] = *(const bf16x8*)(s1 + ks * 32);
        }
    }

#pragma unroll
    for (int ct = 0; ct < NCT; ++ct) {
        f32x4 acc0 = {0.f, 0.f, 0.f, 0.f};
        f32x4 acc1 = {0.f, 0.f, 0.f, 0.f};
        const u16* wp = &wl[(ct * 16 + cl) * WROW + quad * 8];
#pragma unroll
        for (int ks = 0; ks < KS; ++ks) {
            bf16x8 bfrag = *(const bf16x8*)(wp + ks * 32);
            acc0 = __builtin_amdgcn_mfma_f32_16x16x32_bf16(afrag[0][ks], bfrag, acc0, 0, 0, 0);
            acc1 = __builtin_amdgcn_mfma_f32_16x16x32_bf16(afrag[1][ks], bfrag, acc1, 0, 0, 0);
        }
        int gc = ct * 16 + cl;
        float bv = bias[gc];
#pragma unroll
        for (int tile = 0; tile < 2; ++tile) {
            f32x4 a = tile ? acc1 : acc0;
#pragma unroll
            for (int r = 0; r < 4; ++r) {
                int row = rbase + tile * 16 + quad * 4 + r;
                if (row < nrows)
                    outp[(size_t)row * COLS + gc] = f2bf(fmaxf(a[r] + bv, 0.f));
            }
        }
    }
}

// ---------------------------------------------------------------- dual GEMM (layer 2)
// [outA | outB](bf16) = xb @ Wb.T ; outB += bias. Wb [2*COLS][K] bf16.
template <int K, int COLS>
__global__ __launch_bounds__(256) void gemm_mfma(const u16* __restrict__ xb,
                                                 const u16* __restrict__ Wb,
                                                 const float* __restrict__ bias,
                                                 u16* __restrict__ outA,
                                                 u16* __restrict__ outB,
                                                 int nrows) {
    constexpr int NCOL = 2 * COLS;
    constexpr int NCT  = NCOL / 16;
    constexpr int KS   = K / 32;
    constexpr int WROW = K + 8;
    __shared__ u16 wl[NCOL * WROW];

    const int t = threadIdx.x;
    for (int i = t; i < NCOL * (K / 8); i += 256) {
        int r = i / (K / 8), p = i % (K / 8);
        *(uint4*)&wl[r * WROW + p * 8] = *(const uint4*)&Wb[(size_t)r * K + p * 8];
    }
    __syncthreads();

    const int wv    = t >> 6;
    const int lane  = t & 63;
    const int cl    = lane & 15;
    const int quad  = lane >> 4;
    const int rbase = blockIdx.x * 128 + wv * 32;

    bf16x8 afrag[2][KS];
#pragma unroll
    for (int tile = 0; tile < 2; ++tile) {
        int r = rbase + tile * 16 + cl;
        const u16* src = xb + (size_t)min(r, nrows - 1) * K + quad * 8;
#pragma unroll
        for (int ks = 0; ks < KS; ++ks)
            afrag[tile][ks] = *(const bf16x8*)(src + ks * 32);
    }

#pragma unroll
    for (int ct = 0; ct < NCT; ++ct) {
        f32x4 acc0 = {0.f, 0.f, 0.f, 0.f};
        f32x4 acc1 = {0.f, 0.f, 0.f, 0.f};
        const u16* wp = &wl[(ct * 16 + cl) * WROW + quad * 8];
#pragma unroll
        for (int ks = 0; ks < KS; ++ks) {
            bf16x8 bfrag = *(const bf16x8*)(wp + ks * 32);
            acc0 = __builtin_amdgcn_mfma_f32_16x16x32_bf16(afrag[0][ks], bfrag, acc0, 0, 0, 0);
            acc1 = __builtin_amdgcn_mfma_f32_16x16x32_bf16(afrag[1][ks], bfrag, acc1, 0, 0, 0);
        }
        int gc = ct * 16 + cl;
        bool isA = gc < COLS;
        float bv = isA ? 0.f : bias[gc - COLS];
        u16* dst = isA ? (outA + gc) : (outB + (gc - COLS));
#pragma unroll
        for (int tile = 0; tile < 2; ++tile) {
            f32x4 a = tile ? acc1 : acc0;
#pragma unroll
            for (int r = 0; r < 4; ++r) {
                int row = rbase + tile * 16 + quad * 4 + r;
                if (row < nrows) dst[(size_t)row * COLS] = f2bf(a[r] + bv);
            }
        }
    }
}

// ---------------------------------------------------------------- aggregate
// out[n] = (sum_{s in csr_pad[n]} gl[s]) * inv_deg[n]  [+ other[n]] ; bf16 in/out.
// Padded CSR: node's edges at csr[node*CAP .. node*CAP+deg).
template <int C, bool HAS_OTHER>
__global__ __launch_bounds__(256) void agg_bf(const u16* __restrict__ gl,
                                              const u16* __restrict__ other,
                                              const int* __restrict__ cnt,
                                              const int* __restrict__ csr,
                                              const float* __restrict__ inv_deg,
                                              u16* __restrict__ outp, int n) {
    constexpr int G = C / 8;                 // lanes per node
    int t = threadIdx.x;
    int node = blockIdx.x * (256 / G) + t / G;
    int l = t % G;
    if (node >= n) return;

    int deg = min(cnt[node], CAP);
    const int* sp = csr + (size_t)node * CAP;
    float a[8] = {0.f, 0.f, 0.f, 0.f, 0.f, 0.f, 0.f, 0.f};
    const size_t coff = (size_t)l * 8;
    for (int p = 0; p < deg; ++p) {
        int s = sp[p];
        uint4 v = *(const uint4*)(gl + (size_t)s * C + coff);
        a[0] += bflo(v.x); a[1] += bfhi(v.x);
        a[2] += bflo(v.y); a[3] += bfhi(v.y);
        a[4] += bflo(v.z); a[5] += bfhi(v.z);
        a[6] += bflo(v.w); a[7] += bfhi(v.w);
    }
    float id = inv_deg[node];
    float r[8];
    if (HAS_OTHER) {
        uint4 o = *(const uint4*)(other + (size_t)node * C + coff);
        r[0] = fmaf(a[0], id, bflo(o.x)); r[1] = fmaf(a[1], id, bfhi(o.x));
        r[2] = fmaf(a[2], id, bflo(o.y)); r[3] = fmaf(a[3], id, bfhi(o.y));
        r[4] = fmaf(a[4], id, bflo(o.z)); r[5] = fmaf(a[5], id, bfhi(o.z));
        r[6] = fmaf(a[6], id, bflo(o.w)); r[7] = fmaf(a[7], id, bfhi(o.w));
    } else {
#pragma unroll
        for (int j = 0; j < 8; ++j) r[j] = a[j] * id;
    }
    uint4 w;
    w.x = (unsigned)f2bf(r[0]) | ((unsigned)f2bf(r[1]) << 16);
    w.y = (unsigned)f2bf(r[2]) | ((unsigned)f2bf(r[3]) << 16);
    w.z = (unsigned)f2bf(r[4]) | ((unsigned)f2bf(r[5]) << 16);
    w.w = (unsigned)f2bf(r[6]) | ((unsigned)f2bf(r[7]) << 16);
    *(uint4*)(outp + (size_t)node * C + coff) = w;
}

// ---------------------------------------------------------------- decode (bf16 z)
__global__ __launch_bounds__(256) void decode(const u16* __restrict__ z,
                                              const int* __restrict__ ei,
                                              float* __restrict__ out, int E, int n) {
    int t = blockIdx.x * 256 + threadIdx.x;
    int e = t >> 3, l = t & 7;
    if (e >= E) return;
    int s = __builtin_nontemporal_load(ei + e);
    int d = __builtin_nontemporal_load(ei + (size_t)E + e);
    float p = 0.f;
    if ((unsigned)s < (unsigned)n && (unsigned)d < (unsigned)n) {
        uint4 a = *(const uint4*)(z + (size_t)s * OUT_C + l * 8);
        uint4 b = *(const uint4*)(z + (size_t)d * OUT_C + l * 8);
        p  = bflo(a.x) * bflo(b.x) + bfhi(a.x) * bfhi(b.x);
        p += bflo(a.y) * bflo(b.y) + bfhi(a.y) * bfhi(b.y);
        p += bflo(a.z) * bflo(b.z) + bfhi(a.z) * bfhi(b.z);
        p += bflo(a.w) * bflo(b.w) + bfhi(a.w) * bfhi(b.w);
    }
    p += __shfl_xor(p, 4);
    p += __shfl_xor(p, 2);
    p += __shfl_xor(p, 1);
    if (l == 0) out[e] = p;
}

// ---------------------------------------------------------------- launch
extern "C" void kernel_launch(void* const* d_in, const int* in_sizes, int n_in,
                              void* d_out, int out_size, void* d_ws, size_t ws_size,
                              hipStream_t stream) {
    const float* x   = (const float*)d_in[0];
    const int*   ei  = (const int*)d_in[1];
    const float* w1l = (const float*)d_in[2];
    const float* w1r = (const float*)d_in[3];
    const float* b1  = (const float*)d_in[4];
    const float* w2l = (const float*)d_in[5];
    const float* w2r = (const float*)d_in[6];
    const float* b2  = (const float*)d_in[7];
    float*       out = (float*)d_out;

    const int N = in_sizes[0] / IN_C;
    const int E = in_sizes[1] / 2;

    auto alignup = [](size_t v) { return (v + 255) & ~(size_t)255; };
    char* p = (char*)d_ws;
    int*   cnt       = (int*)p;   p += alignup((size_t)N * 4);
    float* inv_deg   = (float*)p; p += alignup((size_t)N * 4);
    int*   csr       = (int*)p;   p += alignup((size_t)N * CAP * 4);   // 25.6 MB
    u16*   Wb1       = (u16*)p;   p += alignup((size_t)HID_C * 2 * IN_C * 2);
    u16*   Wb2       = (u16*)p;   p += alignup((size_t)2 * OUT_C * HID_C * 2);
    u16*   xb        = (u16*)p;   p += alignup((size_t)N * IN_C * 2);  // dead after gemm_l1
    u16*   ag1       = (u16*)p;   p += alignup((size_t)N * HID_C * 2); // dead after gemm_l1
    u16*   hb        = (u16*)p;   p += alignup((size_t)N * HID_C * 2);
    // alias late-stage buffers onto dead xb/ag1 regions
    u16*   hlb       = xb;                              // N*OUT_C*2 = 12.8 MB
    u16*   hrb       = xb + (size_t)N * OUT_C;          // second half of xb region
    u16*   zb        = ag1;                             // 12.8 MB in ag1 region

    const int nslice = (E + SLICE_E - 1) / SLICE_E;

    // converts (independent of CSR)
    cvt_x<<<(N * IN_C / 4 + 255) / 256, 256, 0, stream>>>(x, xb, N * IN_C / 4);
    cvt_w<<<192, 256, 0, stream>>>(w1l, w1r, w2l, w2r, Wb1, Wb2);

    // padded-CSR build: ONE edge pass (count==fill), XCD-partitioned by dst range
    hipMemsetAsync(cnt, 0, (size_t)N * 4, stream);
    fill_pad<<<nslice * NPART, 256, 0, stream>>>(ei, cnt, csr, E, N);
    deg_inv<<<(N + 255) / 256, 256, 0, stream>>>(cnt, inv_deg, N);

    const int rb = (N + 127) / 128;

    // ag1 = mean_agg(xb)
    agg_bf<HID_C, false><<<(N + 15) / 16, 256, 0, stream>>>(xb, nullptr, cnt, csr,
                                                            inv_deg, ag1, N);
    // h = relu([ag1|xb] @ [w1l|w1r].T + b1)
    gemm_l1<<<rb, 256, 0, stream>>>(ag1, xb, Wb1, b1, hb, N);

    // hl = h@w2l.T ; hr = h@w2r.T + b2
    gemm_mfma<HID_C, OUT_C><<<rb, 256, 0, stream>>>(hb, Wb2, b2, hlb, hrb, N);
    // z = agg(hl)/deg + hr  (bf16)
    agg_bf<OUT_C, true><<<(N + 31) / 32, 256, 0, stream>>>(hlb, hrb, cnt, csr,
                                                           inv_deg, zb, N);

    // decode (bf16 z)
    decode<<<((size_t)E * 8 + 255) / 256, 256, 0, stream>>>(zb, ei, out, E, N);
}